// Round 3
// baseline (393.932 us; speedup 1.0000x reference)
//
#include <hip/hip_runtime.h>

// Problem: B=16384, F=1024, H=64, D=256, TE=CE=4.
// I/O fp32; internal fp16 MFMA, fp32 accum. out = (outA,outS,outB) [3][B][256].
//
// R3: the R2 fused kernel was sync-bound: ~3800 cy per barrier-step x 120 steps
// (m233's 2-phase constant), 1 block/CU = no TLP. New structure:
//  - weights (W1, W2, gate) load DIRECT global->register, parity double-buffered
//    (L2-hot, zero reuse within block -> LDS staging was pure overhead)
//  - only x staged via global_load_lds (shared by 4 waves), 3-deep rotation
//  - ONE barrier per l1 k-step (stage issued post-barrier), ZERO barriers in l2
//  - 512 blocks x 256 thr (32 rows each), 75.5 KB LDS -> 2 blocks/CU for TLP
//  - pack_kernel rewritten as coalesced LDS transpose

#define BB 16384
#define FF 1024

typedef _Float16 f16;
typedef __fp16 h16x2 __attribute__((ext_vector_type(2)));   // cvt_pkrtz return type
typedef _Float16 f16x4 __attribute__((ext_vector_type(4)));
typedef _Float16 f16x8 __attribute__((ext_vector_type(8)));
typedef float f32x4 __attribute__((ext_vector_type(4)));

__device__ __forceinline__ void load_lds16(const void* g, void* l) {
    __builtin_amdgcn_global_load_lds(
        (const __attribute__((address_space(1))) unsigned int*)g,
        (__attribute__((address_space(3))) unsigned int*)l, 16, 0, 0);
}

__device__ __forceinline__ f16x8 pack8(float4 lo, float4 hi) {
    union { f16x8 v; h16x2 p[4]; } u;
    u.p[0] = __builtin_amdgcn_cvt_pkrtz(lo.x, lo.y);
    u.p[1] = __builtin_amdgcn_cvt_pkrtz(lo.z, lo.w);
    u.p[2] = __builtin_amdgcn_cvt_pkrtz(hi.x, hi.y);
    u.p[3] = __builtin_amdgcn_cvt_pkrtz(hi.z, hi.w);
    return u.v;
}

#define SBAR() __builtin_amdgcn_sched_barrier(0)

// ---------------------------------------------------------------------------
// Pack (coalesced transposes):
//   Wp[g][c=e*64+h][k] f16   from W1g[e][k][h]   (3 x 256 x 1024)
//   W2T[g][e][d][h]   f16    from W2g[e][h][d]   (3 x 4 x 256 x 64)
//   Gp[g][c<16][k]    f16    from Wgg[k][c], zero-padded (3 x 16 x 1024)
// Blocks: 0..191 Wp (3g x 4e x 16 ktiles), 192..239 W2T (3 x 4 x 4 dtiles),
//         240..242 Gp.
// ---------------------------------------------------------------------------
__global__ __launch_bounds__(256) void pack_kernel(
    const float* __restrict__ W1A, const float* __restrict__ W1S, const float* __restrict__ W1B,
    const float* __restrict__ W2A, const float* __restrict__ W2S, const float* __restrict__ W2B,
    const float* __restrict__ WgA, const float* __restrict__ WgS, const float* __restrict__ WgB,
    f16* __restrict__ Wp, f16* __restrict__ W2T, f16* __restrict__ Gp)
{
    __shared__ float T[64 * 65];
    const int b = blockIdx.x, tid = threadIdx.x;

    if (b < 192) {               // Wp: transpose 64k x 64h tile of W1[e][k][h]
        int g = b >> 6, e = (b >> 4) & 3, k0 = (b & 15) * 64;
        const float* W1 = (g == 0) ? W1A : ((g == 1) ? W1S : W1B);
        const float* src = W1 + e * 65536 + k0 * 64;
#pragma unroll
        for (int r = 0; r < 4; ++r) {
            int slot = r * 256 + tid, kr = slot >> 4, h4 = slot & 15;
            float4 v = *(const float4*)(src + kr * 64 + h4 * 4);
            T[(h4 * 4 + 0) * 65 + kr] = v.x;
            T[(h4 * 4 + 1) * 65 + kr] = v.y;
            T[(h4 * 4 + 2) * 65 + kr] = v.z;
            T[(h4 * 4 + 3) * 65 + kr] = v.w;
        }
        __syncthreads();
        f16* dst = Wp + g * 262144 + e * 64 * 1024 + k0;
#pragma unroll
        for (int r = 0; r < 4; ++r) {
            int slot = r * 256 + tid, h = slot >> 4, k4 = slot & 15;
            f16x4 o;
            o[0] = (f16)T[h * 65 + k4 * 4 + 0];
            o[1] = (f16)T[h * 65 + k4 * 4 + 1];
            o[2] = (f16)T[h * 65 + k4 * 4 + 2];
            o[3] = (f16)T[h * 65 + k4 * 4 + 3];
            *(f16x4*)(dst + h * 1024 + k4 * 4) = o;
        }
    } else if (b < 240) {        // W2T: transpose 64h x 64d tile of W2[e][h][d]
        int bb = b - 192;
        int g = bb >> 4, e = (bb >> 2) & 3, d0 = (bb & 3) * 64;
        const float* W2 = (g == 0) ? W2A : ((g == 1) ? W2S : W2B);
        const float* src = W2 + e * 16384 + d0;
#pragma unroll
        for (int r = 0; r < 4; ++r) {
            int slot = r * 256 + tid, hr = slot >> 4, d4 = slot & 15;
            float4 v = *(const float4*)(src + hr * 256 + d4 * 4);
            T[(d4 * 4 + 0) * 65 + hr] = v.x;
            T[(d4 * 4 + 1) * 65 + hr] = v.y;
            T[(d4 * 4 + 2) * 65 + hr] = v.z;
            T[(d4 * 4 + 3) * 65 + hr] = v.w;
        }
        __syncthreads();
        f16* dst = W2T + (g * 4 + e) * 16384 + d0 * 64;
#pragma unroll
        for (int r = 0; r < 4; ++r) {
            int slot = r * 256 + tid, dl = slot >> 4, h4 = slot & 15;
            f16x4 o;
            o[0] = (f16)T[dl * 65 + h4 * 4 + 0];
            o[1] = (f16)T[dl * 65 + h4 * 4 + 1];
            o[2] = (f16)T[dl * 65 + h4 * 4 + 2];
            o[3] = (f16)T[dl * 65 + h4 * 4 + 3];
            *(f16x4*)(dst + dl * 64 + h4 * 4) = o;
        }
    } else {                     // Gp
        int g = b - 240;
        int ng = (g == 1) ? 12 : 8;
        const float* Wg = (g == 0) ? WgA : ((g == 1) ? WgS : WgB);
#pragma unroll 4
        for (int r = 0; r < 64; ++r) {
            int idx = r * 256 + tid;          // [c][k], c = idx>>10
            int c = idx >> 10, k = idx & 1023;
            Gp[g * 16384 + idx] = (c < ng) ? (f16)Wg[k * ng + c] : (f16)0.0f;
        }
    }
}

// ---------------------------------------------------------------------------
// Fused l1+l2. grid 512, block 256 (4 waves), dynamic LDS 77312 B.
// LDS: hls[3][32][256] f16 @0 (49152) | Xs[3][32x64 f32] @49152 (24576,
//      aliased by b2s[3][1024] f32 in l2) | gsh[32][28] f32 @73728 (3584)
// l1: 48 k-steps (3 groups x 16, BK=64). Per step per wave:
//   pre-wait:  issue W1+gate frags for t+1 (10 global b128 -> regs)
//   wait vmcnt(12) lgkmcnt(0); s_barrier      (retires X(t), Wf(t))
//   post-bar:  stage_x(t+2) (2 global_load_lds)
//   compute:   8 ds_read_b128 + cvt + 16+4 MFMA
// l2: 12 (gi,e) pairs, W2 frags direct-to-reg, barrier-free (vmcnt(8) only).
// ---------------------------------------------------------------------------
__global__ __launch_bounds__(256, 2) void fused_kernel(
    const float* __restrict__ xA, const float* __restrict__ xS, const float* __restrict__ xB,
    const float* __restrict__ b1A, const float* __restrict__ b1S, const float* __restrict__ b1B,
    const float* __restrict__ bgA, const float* __restrict__ bgS, const float* __restrict__ bgB,
    const float* __restrict__ b2A, const float* __restrict__ b2S, const float* __restrict__ b2B,
    const f16* __restrict__ Wp,      // [3][256][1024]
    const f16* __restrict__ Gp,      // [3][16][1024]
    const f16* __restrict__ W2T,     // [3][4][256][64]
    float* __restrict__ out)         // [3][B][256]
{
    extern __shared__ char smem[];
    f16*   hls = (f16*)smem;                   // [3][32][256]
    float* Xs  = (float*)(smem + 49152);       // l1: [3][2048]
    float* b2s = (float*)(smem + 49152);       // l2 alias: [3][1024]
    float* gsh = (float*)(smem + 73728);       // [32][28]

    const int tid  = threadIdx.x;
    const int lane = tid & 63;
    const int w    = tid >> 6;
    const int lrow = lane & 15;
    const int quad = lane >> 4;
    const int row0 = blockIdx.x * 32;
    const int wn   = w * 64;                   // wave col/d quarter

    // bias preloads (retire before pipeline; later compiler waits are no-ops)
    float b1vA[4], b1vS[4], b1vB[4];
#pragma unroll
    for (int j = 0; j < 4; ++j) {
        int c = wn + j * 16 + lrow;
        b1vA[j] = b1A[c]; b1vS[j] = b1S[c]; b1vB[j] = b1B[c];
    }
    float bgv0 = (lrow < 8)  ? bgA[lrow] : 0.0f;
    float bgv1 = (lrow < 12) ? bgS[lrow] : 0.0f;
    float bgv2 = (lrow < 8)  ? bgB[lrow] : 0.0f;

    // ---- staging / issue helpers --------------------------------------
    auto stage_x = [&](int tt) {               // 8KB x-tile, 2 load_lds/thread
        int g = tt >> 4, kb = (tt & 15) * 64;
        const float* xg = (g == 0) ? xA : ((g == 1) ? xS : xB);
        float* dstb = Xs + (tt % 3) * 2048;
#pragma unroll
        for (int r = 0; r < 2; ++r) {
            int s = r * 256 + tid;
            int m = s >> 4, slot = s & 15;
            int seg = slot ^ (m & 15);         // inverse-swizzled source
            load_lds16(xg + (size_t)(row0 + m) * FF + kb + seg * 4, dstb + s * 4);
        }
    };
    auto issue_wf = [&](int tt, f16x8 (&wf)[2][4], f16x8 (&gb)[2]) {  // 10 loads
        int g = tt >> 4, kb = (tt & 15) * 64;
        const f16* ws = Wp + (size_t)g * 262144;
        const f16* gs = Gp + (size_t)g * 16384;
#pragma unroll
        for (int kk = 0; kk < 2; ++kk) {
#pragma unroll
            for (int j = 0; j < 4; ++j)
                wf[kk][j] = *(const f16x8*)(ws + (size_t)(wn + j * 16 + lrow) * 1024 + kb + kk * 32 + quad * 8);
            gb[kk] = *(const f16x8*)(gs + (size_t)lrow * 1024 + kb + kk * 32 + quad * 8);
        }
    };

    f32x4 acc[2][4] = {};
    f32x4 gacc[2] = {};

    auto compute = [&](int t, f16x8 (&wf)[2][4], f16x8 (&gb)[2]) {
        const float* xb = Xs + (t % 3) * 2048;
#pragma unroll
        for (int kk = 0; kk < 2; ++kk) {
            f16x8 af[2];
#pragma unroll
            for (int i = 0; i < 2; ++i) {
                int m = i * 16 + lrow;
                int slot = (kk * 8 + quad * 2) ^ (m & 15);
                const float* rp = xb + m * 64;
                float4 lo = *(const float4*)(rp + slot * 4);
                float4 hi = *(const float4*)(rp + (slot ^ 1) * 4);
                af[i] = pack8(lo, hi);
            }
#pragma unroll
            for (int i = 0; i < 2; ++i) {
#pragma unroll
                for (int j = 0; j < 4; ++j)
                    acc[i][j] = __builtin_amdgcn_mfma_f32_16x16x32_f16(af[i], wf[kk][j], acc[i][j], 0, 0, 0);
                // all waves compute gate MFMA (keeps vm-issue counts uniform)
                gacc[i] = __builtin_amdgcn_mfma_f32_16x16x32_f16(af[i], gb[kk], gacc[i], 0, 0, 0);
            }
        }
    };

    auto h_write = [&](int g, const float (&bv)[4]) {
        f16* hb = hls + g * 8192;
#pragma unroll
        for (int j = 0; j < 4; ++j) {
            int col = wn + j * 16 + lrow;
            float bias = bv[j];
#pragma unroll
            for (int i = 0; i < 2; ++i)
#pragma unroll
                for (int r = 0; r < 4; ++r) {
                    int row = i * 16 + quad * 4 + r;
                    float v = fmaxf(acc[i][j][r] + bias, 0.0f);
                    hb[row * 256 + (col ^ ((row & 7) << 3))] = (f16)v;
                }
        }
#pragma unroll
        for (int i = 0; i < 2; ++i)
#pragma unroll
            for (int j = 0; j < 4; ++j)
                acc[i][j] = (f32x4){0.f, 0.f, 0.f, 0.f};
    };

    auto softmax_store = [&](float bgc, int ng, int goff) {   // wave 0 only
        bool valid = (lrow < ng);
#pragma unroll
        for (int i = 0; i < 2; ++i)
#pragma unroll
            for (int r = 0; r < 4; ++r) {
                int row = i * 16 + quad * 4 + r;
                float logit = valid ? (gacc[i][r] + bgc) : -1e30f;
                float mx = logit;
#pragma unroll
                for (int m = 1; m < 16; m <<= 1)
                    mx = fmaxf(mx, __shfl_xor(mx, m, 16));
                float ev = valid ? __expf(logit - mx) : 0.0f;
                float sum = ev;
#pragma unroll
                for (int m = 1; m < 16; m <<= 1)
                    sum += __shfl_xor(sum, m, 16);
                if (valid) gsh[row * 28 + goff + lrow] = ev / sum;
            }
    };

    // ---- l1 pipeline ---------------------------------------------------
    f16x8 wfA[2][4], gbA[2], wfB[2][4], gbB[2];

    stage_x(0); SBAR();
    issue_wf(0, wfA, gbA); SBAR();
    stage_x(1); SBAR();

    auto l1_step = [&](int t, f16x8 (&wfC)[2][4], f16x8 (&gbC)[2],
                       f16x8 (&wfN)[2][4], f16x8 (&gbN)[2]) {
        issue_wf(t + 1, wfN, gbN);
        SBAR();
        asm volatile("s_waitcnt vmcnt(12) lgkmcnt(0)" ::: "memory");
        SBAR();
        __builtin_amdgcn_s_barrier();
        SBAR();
        stage_x(t + 2);
        SBAR();
        compute(t, wfC, gbC);
    };

    for (int tb = 0; tb < 46; tb += 2) {
        l1_step(tb, wfA, gbA, wfB, gbB);
        int t1 = tb + 1;
        l1_step(t1, wfB, gbB, wfA, gbA);
        if (t1 == 15) {
            h_write(0, b1vA);
            if (w == 0) softmax_store(bgv0, 8, 0);
#pragma unroll
            for (int i = 0; i < 2; ++i) gacc[i] = (f32x4){0.f, 0.f, 0.f, 0.f};
        } else if (t1 == 31) {
            h_write(1, b1vS);
            if (w == 0) softmax_store(bgv1, 12, 8);
#pragma unroll
            for (int i = 0; i < 2; ++i) gacc[i] = (f32x4){0.f, 0.f, 0.f, 0.f};
        }
    }

    // W2 fragment issue (l2)
    f16x8 wf2A[2][4], wf2B[2][4];
    auto issue_wf2 = [&](int p, f16x8 (&wf)[2][4]) {          // 8 loads
        int gi = p >> 2, e = p & 3;
        const f16* w2 = W2T + (size_t)(gi * 4 + e) * 16384;
#pragma unroll
        for (int kk = 0; kk < 2; ++kk)
#pragma unroll
            for (int j = 0; j < 4; ++j)
                wf[kk][j] = *(const f16x8*)(w2 + (size_t)(wn + j * 16 + lrow) * 64 + kk * 32 + quad * 8);
    };

    // peeled t=46 (cur=A)
    issue_wf(47, wfB, gbB);
    SBAR();
    asm volatile("s_waitcnt vmcnt(12) lgkmcnt(0)" ::: "memory");
    SBAR(); __builtin_amdgcn_s_barrier(); SBAR();
    compute(46, wfA, gbA);

    // peeled t=47 (cur=B): post-barrier, start l2 staging (b2 -> LDS alias of Xs)
    asm volatile("s_waitcnt vmcnt(0) lgkmcnt(0)" ::: "memory");
    SBAR(); __builtin_amdgcn_s_barrier(); SBAR();
#pragma unroll
    for (int r = 0; r < 3; ++r) {
        const float* src = (r == 0) ? (b2A + tid * 4) : ((r == 1) ? (b2S + tid * 4) : (b2B + tid * 4));
        load_lds16(src, b2s + r * 1024 + tid * 4);
    }
    SBAR();
    issue_wf2(0, wf2A);
    SBAR();
    compute(47, wfB, gbB);
    h_write(2, b1vB);
    if (w == 0) softmax_store(bgv2, 8, 20);

    // transition: retire b2 (keep Wf2(0) in flight), drain LDS writes, barrier
    asm volatile("s_waitcnt vmcnt(8) lgkmcnt(0)" ::: "memory");
    SBAR(); __builtin_amdgcn_s_barrier(); SBAR();

    // ---- l2: 12 pairs, barrier-free ------------------------------------
    f32x4 oA[2][4] = {}, oS[2][4] = {}, oB[2][4] = {};

    auto l2_pair = [&](int p, f16x8 (&wfC)[2][4], f16x8 (&wfN)[2][4]) {
        if (p < 11) { issue_wf2(p + 1, wfN); }
        SBAR();
        if (p < 11) { asm volatile("s_waitcnt vmcnt(8)" ::: "memory"); }
        else        { asm volatile("s_waitcnt vmcnt(0)" ::: "memory"); }
        SBAR();
        const int gi = p >> 2, e = p & 3;
        f32x4 eacc[2][4] = {};
#pragma unroll
        for (int kk = 0; kk < 2; ++kk) {
            f16x8 af[2];
#pragma unroll
            for (int i = 0; i < 2; ++i) {
                int m = i * 16 + lrow;
                int col = (e * 64 + kk * 32 + quad * 8) ^ ((m & 7) << 3);
                af[i] = *(const f16x8*)(hls + gi * 8192 + m * 256 + col);
            }
#pragma unroll
            for (int i = 0; i < 2; ++i)
#pragma unroll
                for (int j = 0; j < 4; ++j)
                    eacc[i][j] = __builtin_amdgcn_mfma_f32_16x16x32_f16(af[i], wfC[kk][j], eacc[i][j], 0, 0, 0);
        }
#pragma unroll
        for (int j = 0; j < 4; ++j) {
            float bias = b2s[gi * 1024 + e * 256 + wn + j * 16 + lrow];
#pragma unroll
            for (int i = 0; i < 2; ++i)
#pragma unroll
                for (int r = 0; r < 4; ++r) {
                    int row = i * 16 + quad * 4 + r;
                    float v = fmaxf(eacc[i][j][r] + bias, 0.0f);
                    if (gi == 0) {
                        oA[i][j][r] += gsh[row * 28 + e] * v;
                        oS[i][j][r] += gsh[row * 28 + 8 + e] * v;
                    } else if (gi == 1) {
                        oA[i][j][r] += gsh[row * 28 + 4 + e] * v;
                        oS[i][j][r] += gsh[row * 28 + 12 + e] * v;
                        oB[i][j][r] += gsh[row * 28 + 24 + e] * v;
                    } else {
                        oS[i][j][r] += gsh[row * 28 + 16 + e] * v;
                        oB[i][j][r] += gsh[row * 28 + 20 + e] * v;
                    }
                }
        }
    };

#pragma unroll
    for (int pp = 0; pp < 6; ++pp) {
        l2_pair(2 * pp, wf2A, wf2B);
        l2_pair(2 * pp + 1, wf2B, wf2A);
    }

    // epilogue
#pragma unroll
    for (int j = 0; j < 4; ++j) {
        int d = wn + j * 16 + lrow;
#pragma unroll
        for (int i = 0; i < 2; ++i)
#pragma unroll
            for (int r = 0; r < 4; ++r) {
                int row = row0 + i * 16 + quad * 4 + r;
                out[((size_t)0 * BB + row) * 256 + d] = oA[i][j][r];
                out[((size_t)1 * BB + row) * 256 + d] = oS[i][j][r];
                out[((size_t)2 * BB + row) * 256 + d] = oB[i][j][r];
            }
    }
}

// ---------------------------------------------------------------------------
extern "C" void kernel_launch(void* const* d_in, const int* in_sizes, int n_in,
                              void* d_out, int out_size, void* d_ws, size_t ws_size,
                              hipStream_t stream)
{
    (void)in_sizes; (void)n_in; (void)out_size; (void)ws_size;

    const float* xA  = (const float*)d_in[0];
    const float* xS  = (const float*)d_in[1];
    const float* xB  = (const float*)d_in[2];
    const float* W1A = (const float*)d_in[3];
    const float* b1A = (const float*)d_in[4];
    const float* W2A = (const float*)d_in[5];
    const float* b2A = (const float*)d_in[6];
    const float* W1S = (const float*)d_in[7];
    const float* b1S = (const float*)d_in[8];
    const float* W2S = (const float*)d_in[9];
    const float* b2S = (const float*)d_in[10];
    const float* W1B = (const float*)d_in[11];
    const float* b1B = (const float*)d_in[12];
    const float* W2B = (const float*)d_in[13];
    const float* b2B = (const float*)d_in[14];
    const float* WgA = (const float*)d_in[15];
    const float* bgA = (const float*)d_in[16];
    const float* WgB = (const float*)d_in[17];
    const float* bgB = (const float*)d_in[18];
    const float* WgS = (const float*)d_in[19];
    const float* bgS = (const float*)d_in[20];

    char* ws = (char*)d_ws;
    f16* Wp  = (f16*)(ws);                 // 1,572,864 B
    f16* W2T = (f16*)(ws + 0x180000);      //   393,216 B
    f16* Gp  = (f16*)(ws + 0x1E0000);      //    98,304 B

    pack_kernel<<<243, 256, 0, stream>>>(W1A, W1S, W1B, W2A, W2S, W2B,
                                         WgA, WgS, WgB, Wp, W2T, Gp);
    fused_kernel<<<512, 256, 77312, stream>>>(
        xA, xS, xB, b1A, b1S, b1B, bgA, bgS, bgB, b2A, b2S, b2B,
        Wp, Gp, W2T, (float*)d_out);
}

// Round 4
// 368.231 us; speedup vs baseline: 1.0698x; 1.0698x over previous
//
#include <hip/hip_runtime.h>

// Problem: B=16384, F=1024, H=64, D=256, TE=CE=4.
// I/O fp32; internal fp16 MFMA, fp32 accum. out = (outA,outS,outB) [3][B][256].
//
// R4: back to split l1/l2 (fused 32-row blocks were L2-BW-bound on W1 re-stream:
// ~2GB L2 traffic; 128-row blocks amortize W but h no longer fits LDS).
// l1 = R1's pipelined 128x128 kernel with the gate-staging poison removed:
// gate weights repacked to contiguous [c][k] 1KB k-tiles, staged via ONE
// global_load_lds per thread (async, uniform per-wave counts -> clean
// vmcnt(7)/vmcnt(6) counted prefetch). l2 = R1's l2 (bias-first ordering,
// h-slice prefetch, counted vmcnt) verbatim. pack = R3's coalesced transpose.

#define BB 16384
#define FF 1024

typedef _Float16 f16;
typedef __fp16 h16x2 __attribute__((ext_vector_type(2)));   // cvt_pkrtz return type
typedef _Float16 f16x4 __attribute__((ext_vector_type(4)));
typedef _Float16 f16x8 __attribute__((ext_vector_type(8)));
typedef float f32x4 __attribute__((ext_vector_type(4)));

__device__ __forceinline__ void load_lds16(const void* g, void* l) {
    __builtin_amdgcn_global_load_lds(
        (const __attribute__((address_space(1))) unsigned int*)g,
        (__attribute__((address_space(3))) unsigned int*)l, 16, 0, 0);
}

__device__ __forceinline__ f16x8 pack8(float4 lo, float4 hi) {
    union { f16x8 v; h16x2 p[4]; } u;
    u.p[0] = __builtin_amdgcn_cvt_pkrtz(lo.x, lo.y);
    u.p[1] = __builtin_amdgcn_cvt_pkrtz(lo.z, lo.w);
    u.p[2] = __builtin_amdgcn_cvt_pkrtz(hi.x, hi.y);
    u.p[3] = __builtin_amdgcn_cvt_pkrtz(hi.z, hi.w);
    return u.v;
}

#define SBAR() __builtin_amdgcn_sched_barrier(0)

// ---------------------------------------------------------------------------
// Pack (coalesced transposes):
//   Wp[g][c=e*64+h][k] f16   from W1g[e][k][h]   (3 x 256 x 1024)
//   W2T[g][e][d][h]   f16    from W2g[e][h][d]   (3 x 4 x 256 x 64)
//   Gp[g][kt<32][c<16][kk<32] f16 from Wgg[kt*32+kk][c], zero-pad (3 x 16384)
// Blocks: 0..191 Wp, 192..239 W2T, 240..242 Gp.
// ---------------------------------------------------------------------------
__global__ __launch_bounds__(256) void pack_kernel(
    const float* __restrict__ W1A, const float* __restrict__ W1S, const float* __restrict__ W1B,
    const float* __restrict__ W2A, const float* __restrict__ W2S, const float* __restrict__ W2B,
    const float* __restrict__ WgA, const float* __restrict__ WgS, const float* __restrict__ WgB,
    f16* __restrict__ Wp, f16* __restrict__ W2T, f16* __restrict__ Gp)
{
    __shared__ float T[64 * 65];
    const int b = blockIdx.x, tid = threadIdx.x;

    if (b < 192) {               // Wp: transpose 64k x 64h tile of W1[e][k][h]
        int g = b >> 6, e = (b >> 4) & 3, k0 = (b & 15) * 64;
        const float* W1 = (g == 0) ? W1A : ((g == 1) ? W1S : W1B);
        const float* src = W1 + e * 65536 + k0 * 64;
#pragma unroll
        for (int r = 0; r < 4; ++r) {
            int slot = r * 256 + tid, kr = slot >> 4, h4 = slot & 15;
            float4 v = *(const float4*)(src + kr * 64 + h4 * 4);
            T[(h4 * 4 + 0) * 65 + kr] = v.x;
            T[(h4 * 4 + 1) * 65 + kr] = v.y;
            T[(h4 * 4 + 2) * 65 + kr] = v.z;
            T[(h4 * 4 + 3) * 65 + kr] = v.w;
        }
        __syncthreads();
        f16* dst = Wp + g * 262144 + e * 64 * 1024 + k0;
#pragma unroll
        for (int r = 0; r < 4; ++r) {
            int slot = r * 256 + tid, h = slot >> 4, k4 = slot & 15;
            f16x4 o;
            o[0] = (f16)T[h * 65 + k4 * 4 + 0];
            o[1] = (f16)T[h * 65 + k4 * 4 + 1];
            o[2] = (f16)T[h * 65 + k4 * 4 + 2];
            o[3] = (f16)T[h * 65 + k4 * 4 + 3];
            *(f16x4*)(dst + h * 1024 + k4 * 4) = o;
        }
    } else if (b < 240) {        // W2T: transpose 64h x 64d tile of W2[e][h][d]
        int bb = b - 192;
        int g = bb >> 4, e = (bb >> 2) & 3, d0 = (bb & 3) * 64;
        const float* W2 = (g == 0) ? W2A : ((g == 1) ? W2S : W2B);
        const float* src = W2 + e * 16384 + d0;
#pragma unroll
        for (int r = 0; r < 4; ++r) {
            int slot = r * 256 + tid, hr = slot >> 4, d4 = slot & 15;
            float4 v = *(const float4*)(src + hr * 256 + d4 * 4);
            T[(d4 * 4 + 0) * 65 + hr] = v.x;
            T[(d4 * 4 + 1) * 65 + hr] = v.y;
            T[(d4 * 4 + 2) * 65 + hr] = v.z;
            T[(d4 * 4 + 3) * 65 + hr] = v.w;
        }
        __syncthreads();
        f16* dst = W2T + (g * 4 + e) * 16384 + d0 * 64;
#pragma unroll
        for (int r = 0; r < 4; ++r) {
            int slot = r * 256 + tid, dl = slot >> 4, h4 = slot & 15;
            f16x4 o;
            o[0] = (f16)T[dl * 65 + h4 * 4 + 0];
            o[1] = (f16)T[dl * 65 + h4 * 4 + 1];
            o[2] = (f16)T[dl * 65 + h4 * 4 + 2];
            o[3] = (f16)T[dl * 65 + h4 * 4 + 3];
            *(f16x4*)(dst + dl * 64 + h4 * 4) = o;
        }
    } else {                     // Gp: [g][kt][c][kk]
        int g = b - 240;
        int ng = (g == 1) ? 12 : 8;
        const float* Wg = (g == 0) ? WgA : ((g == 1) ? WgS : WgB);
#pragma unroll 4
        for (int r = 0; r < 64; ++r) {
            int j = r * 256 + tid;            // 0..16383
            int kt = j >> 9, c = (j >> 5) & 15, kk = j & 31;
            Gp[g * 16384 + j] = (c < ng) ? (f16)Wg[(kt * 32 + kk) * ng + c] : (f16)0.0f;
        }
    }
}

// ---------------------------------------------------------------------------
// Layer-1: h_g = relu(x_g @ W1cat_g + b1_g)  -> fp16 h [3][B][256]
// plus fused gate softmax on blockIdx.x==0. 128x128 tile, BK=32, 32 k-steps.
// grid (2,128,3), block 256. Double-buffered LDS, raw barriers, counted vmcnt:
// prefetch distance 1, gate tile staged via ONE load_lds per thread (uniform).
// ---------------------------------------------------------------------------
__global__ __launch_bounds__(256) void l1_kernel(
    const float* __restrict__ xA, const float* __restrict__ xS, const float* __restrict__ xB,
    const float* __restrict__ b1A, const float* __restrict__ b1S, const float* __restrict__ b1B,
    const float* __restrict__ bgA, const float* __restrict__ bgS, const float* __restrict__ bgB,
    const f16* __restrict__ Wp,      // [3][256][1024]
    const f16* __restrict__ Gp,      // [3][32][16][32]
    f16* __restrict__ hbuf,          // [3][B][256]
    float* __restrict__ gates)       // gA[B][8] | gS[B][12] | gB[B][8]
{
    const int g = blockIdx.z;
    const float* x  = (g == 0) ? xA  : ((g == 1) ? xS  : xB);
    const float* b1 = (g == 0) ? b1A : ((g == 1) ? b1S : b1B);
    const float* bg = (g == 0) ? bgA : ((g == 1) ? bgS : bgB);
    const int ng = (g == 1) ? 12 : 8;
    float* gout = gates + ((g == 0) ? (size_t)0
                         : (g == 1) ? (size_t)BB * 8
                                    : (size_t)BB * 8 + (size_t)BB * 12);

    const int row0 = blockIdx.y * 128;
    const int col0 = blockIdx.x * 128;
    const bool do_gate = (blockIdx.x == 0);

    __shared__ __align__(16) float Asf[2][128 * 32];   // fp32 x tile, swizzled segs
    __shared__ __align__(16) f16   Bsh[2][128 * 32];   // f16 W1 [n][k], swizzled
    __shared__ __align__(16) f16   Gs[2][512];         // gate tile [c=16][k=32]

    const int tid  = threadIdx.x;
    const int lane = tid & 63;
    const int wave = tid >> 6;
    const int wm = (wave >> 1) * 64;
    const int wn = (wave & 1) * 64;
    const int lrow = lane & 15;
    const int quad = lane >> 4;

    const f16* Wgrp = Wp + (size_t)g * 256 * 1024;
    const f16* Ggrp = Gp + (size_t)g * 16384;

    f32x4 acc[4][4] = {};
    f32x4 gacc[4] = {};
    const bool my_gate = do_gate && ((wave & 1) == 0);

    // gate tile: 1 KB contiguous (32k x 16c packed [c][k]); each wave stages the
    // whole tile redundantly (same-value race, benign) -> uniform 1 load/thread.
    auto stage_g = [&](int t, int buf) {
        if (do_gate)
            load_lds16(Ggrp + (size_t)t * 512 + lane * 8, &Gs[buf][lane * 8]);
    };
    // 6 load_lds per thread: 4x A (fp32 16KB) + 2x B (f16 8KB).
    auto stage_ab = [&](int t, int buf) {
        int k0 = t * 32;
#pragma unroll
        for (int r = 0; r < 4; ++r) {
            int s = r * 256 + tid;
            int m = s >> 3, slot = s & 7;
            int seg = slot ^ (m & 7);
            load_lds16(x + (size_t)(row0 + m) * FF + k0 + seg * 4, &Asf[buf][s * 4]);
        }
#pragma unroll
        for (int r = 0; r < 2; ++r) {
            int s = r * 256 + tid;
            int m = s >> 2, slot = s & 3;
            int seg = slot ^ ((m >> 1) & 3);
            load_lds16(Wgrp + (size_t)(col0 + m) * FF + k0 + seg * 8, &Bsh[buf][s * 8]);
        }
    };

    // prologue: stage tile 0 (loads stay in flight into iter 0's wait)
    stage_g(0, 0);
    SBAR();
    stage_ab(0, 0);
    SBAR();

    for (int t = 0; t < 32; ++t) {
        const int cur = t & 1;
        if (t < 31) {
            stage_g(t + 1, cur ^ 1);
            SBAR();
            stage_ab(t + 1, cur ^ 1);
            SBAR();
            // queue: [G(t)?,AB(t)6, G(t+1)?,AB(t+1)6] -> retire tile t, keep t+1.
            if (do_gate) { asm volatile("s_waitcnt vmcnt(7) lgkmcnt(0)" ::: "memory"); }
            else         { asm volatile("s_waitcnt vmcnt(6) lgkmcnt(0)" ::: "memory"); }
        } else {
            asm volatile("s_waitcnt vmcnt(0) lgkmcnt(0)" ::: "memory");
        }
        SBAR();
        __builtin_amdgcn_s_barrier();            // tile t visible to all waves
        SBAR();

        f16x8 af[4], bfr[4];
#pragma unroll
        for (int i = 0; i < 4; ++i) {
            int m = wm + i * 16 + lrow;
            const float* rp = &Asf[cur][m * 32];
            int s0 = (2 * quad) ^ (m & 7);
            int s1 = s0 ^ 1;
            float4 lo = *(const float4*)(rp + s0 * 4);   // k = q*8 .. q*8+3
            float4 hi = *(const float4*)(rp + s1 * 4);   // k = q*8+4 .. q*8+7
            af[i] = pack8(lo, hi);
        }
#pragma unroll
        for (int j = 0; j < 4; ++j) {
            int n = wn + j * 16 + lrow;
            int slot = quad ^ ((n >> 1) & 3);
            bfr[j] = *(const f16x8*)(&Bsh[cur][n * 32 + slot * 8]);
        }
#pragma unroll
        for (int i = 0; i < 4; ++i)
#pragma unroll
            for (int j = 0; j < 4; ++j)
                acc[i][j] = __builtin_amdgcn_mfma_f32_16x16x32_f16(af[i], bfr[j], acc[i][j], 0, 0, 0);
        if (my_gate) {
            f16x8 gb = *(const f16x8*)(&Gs[cur][lrow * 32 + quad * 8]);
#pragma unroll
            for (int i = 0; i < 4; ++i)
                gacc[i] = __builtin_amdgcn_mfma_f32_16x16x32_f16(af[i], gb, gacc[i], 0, 0, 0);
        }
        // drain my ds_reads before next stage overwrites buffer cur.
        asm volatile("s_waitcnt lgkmcnt(0)" ::: "memory");
        SBAR();
        __builtin_amdgcn_s_barrier();
        SBAR();
    }

    // epilogue: h = relu(acc + b1), fp16. C/D: col=lane&15, row=quad*4+reg.
#pragma unroll
    for (int j = 0; j < 4; ++j) {
        int c = col0 + wn + j * 16 + lrow;
        float bias = b1[c];
#pragma unroll
        for (int i = 0; i < 4; ++i) {
#pragma unroll
            for (int r = 0; r < 4; ++r) {
                int row = row0 + wm + i * 16 + quad * 4 + r;
                float v = fmaxf(acc[i][j][r] + bias, 0.0f);
                hbuf[((size_t)g * BB + row) * 256 + c] = (f16)v;
            }
        }
    }

    // gate softmax: 16-lane groups share one row's logits (c = lrow)
    if (my_gate) {
        int c = lrow;
        bool valid = (c < ng);
        float bias = valid ? bg[c] : 0.0f;
#pragma unroll
        for (int i = 0; i < 4; ++i) {
#pragma unroll
            for (int r = 0; r < 4; ++r) {
                int row = row0 + wm + i * 16 + quad * 4 + r;
                float logit = valid ? (gacc[i][r] + bias) : -1e30f;
                float mx = logit;
#pragma unroll
                for (int m = 1; m < 16; m <<= 1)
                    mx = fmaxf(mx, __shfl_xor(mx, m, 16));
                float ev = valid ? __expf(logit - mx) : 0.0f;
                float sum = ev;
#pragma unroll
                for (int m = 1; m < 16; m <<= 1)
                    sum += __shfl_xor(sum, m, 16);
                if (valid) gout[(size_t)row * ng + c] = ev / sum;
            }
        }
    }
}

// ---------------------------------------------------------------------------
// Layer-2 + gated combine. grid (256, 3), block 256.
// h slice double-buffered + prefetched one pair ahead; W2T single-buffered;
// bias-first issue order; counted vmcnt(2) keeps h(next) in flight.
// ---------------------------------------------------------------------------
__global__ __launch_bounds__(256) void l2_kernel(
    const f16* __restrict__ hbuf,    // [3][B][256]
    const f16* __restrict__ W2T,     // [3][4][256][64]
    const float* __restrict__ b2A, const float* __restrict__ b2S, const float* __restrict__ b2B,
    const float* __restrict__ gates,
    float* __restrict__ out)         // [3][B][256] (A,S,B)
{
    const int o = blockIdx.y;
    const int row0 = blockIdx.x * 64;
    const int tid = threadIdx.x;
    const int lane = tid & 63;
    const int wave = tid >> 6;
    const int wn = wave * 64;
    const int lrow = lane & 15;
    const int quad = lane >> 4;

    const int ng = (o == 1) ? 12 : 8;
    const float* gp = gates + ((o == 0) ? (size_t)0
                             : (o == 1) ? (size_t)BB * 8
                                        : (size_t)BB * 8 + (size_t)BB * 12);

    __shared__ __align__(16) f16 Ash[2][64 * 64];   // h slice [m][k], swizzled, dbuf
    __shared__ __align__(16) f16 Bsh[256 * 64];     // W2T [d][k], swizzled
    __shared__ float gsh[64 * 12];

    auto group_of = [&](int k) -> int {
        if (o == 0)      return (k < 4) ? 0 : 1;   // concat([EA, ES])
        else if (o == 1) return k >> 2;            // concat([EA, ES, EB])
        else             return (k < 4) ? 2 : 1;   // concat([EB, ES])
    };

    auto stage_h = [&](int k, int buf) {           // 2 load_lds per thread
        int gi = group_of(k), e = k & 3;
        const f16* hs = hbuf + ((size_t)gi * BB + row0) * 256 + e * 64;
#pragma unroll
        for (int r = 0; r < 2; ++r) {
            int s = r * 256 + tid;
            int m = s >> 3, slot = s & 7;
            int seg = slot ^ (m & 7);
            load_lds16(hs + (size_t)m * 256 + seg * 8, &Ash[buf][s * 8]);
        }
    };
    auto stage_w2 = [&](int k) {                   // 8 load_lds per thread
        int gi = group_of(k), e = k & 3;
        const f16* w2 = W2T + (size_t)(gi * 4 + e) * 256 * 64;
#pragma unroll
        for (int r = 0; r < 8; ++r) {
            int s = r * 256 + tid;
            int m = s >> 3, slot = s & 7;
            int seg = slot ^ (m & 7);
            load_lds16(w2 + (size_t)m * 64 + seg * 8, &Bsh[s * 8]);
        }
    };

    // prologue: gates to LDS (self-draining), then prefetch h(0).
    for (int idx = tid; idx < 64 * ng; idx += 256)
        gsh[idx] = gp[(size_t)(row0 + idx / ng) * ng + (idx % ng)];
    SBAR();
    stage_h(0, 0);
    SBAR();

    f32x4 oacc[4][4] = {};

    for (int k = 0; k < ng; ++k) {
        const int cur = k & 1;
        const int gi = group_of(k), e = k & 3;
        const float* b2 = (gi == 0) ? b2A : ((gi == 1) ? b2S : b2B);

        // bias loads FIRST (their compiler wait then never drains the stages)
        float bias4[4];
#pragma unroll
        for (int j = 0; j < 4; ++j)
            bias4[j] = b2[e * 256 + wn + j * 16 + lrow];
        SBAR();

        stage_w2(k);                               // overwrite ok: barrier#2 of k-1 passed
        SBAR();
        if (k + 1 < ng) {
            stage_h(k + 1, cur ^ 1);
            SBAR();
            // outstanding <= h_cur(2)+bias(4)+w2(8)+h_next(2); keep h_next.
            asm volatile("s_waitcnt vmcnt(2) lgkmcnt(0)" ::: "memory");
        } else {
            asm volatile("s_waitcnt vmcnt(0) lgkmcnt(0)" ::: "memory");
        }
        SBAR();
        __builtin_amdgcn_s_barrier();
        SBAR();

        f32x4 eacc[4][4] = {};
#pragma unroll
        for (int kk = 0; kk < 2; ++kk) {
            f16x8 af[4], bfr[4];
#pragma unroll
            for (int i = 0; i < 4; ++i) {
                int rr = i * 16 + lrow;
                int slot = (kk * 4 + quad) ^ (rr & 7);
                af[i] = *(const f16x8*)(&Ash[cur][rr * 64 + slot * 8]);
            }
#pragma unroll
            for (int j = 0; j < 4; ++j) {
                int n = wn + j * 16 + lrow;
                int slot = (kk * 4 + quad) ^ (n & 7);
                bfr[j] = *(const f16x8*)(&Bsh[n * 64 + slot * 8]);
            }
#pragma unroll
            for (int i = 0; i < 4; ++i)
#pragma unroll
                for (int j = 0; j < 4; ++j)
                    eacc[i][j] = __builtin_amdgcn_mfma_f32_16x16x32_f16(af[i], bfr[j], eacc[i][j], 0, 0, 0);
        }

        // oacc += gate[row] * relu(eacc + b2)
#pragma unroll
        for (int j = 0; j < 4; ++j) {
            float bias = bias4[j];
#pragma unroll
            for (int i = 0; i < 4; ++i) {
#pragma unroll
                for (int r = 0; r < 4; ++r) {
                    int rl = i * 16 + quad * 4 + r;
                    float v = fmaxf(eacc[i][j][r] + bias, 0.0f);
                    oacc[i][j][r] += gsh[rl * ng + k] * v;
                }
            }
        }
        asm volatile("s_waitcnt lgkmcnt(0)" ::: "memory");
        SBAR();
        __builtin_amdgcn_s_barrier();             // all waves done with Ash[cur]/Bsh
        SBAR();
    }

#pragma unroll
    for (int j = 0; j < 4; ++j) {
        int d = wn + j * 16 + lrow;
#pragma unroll
        for (int i = 0; i < 4; ++i) {
#pragma unroll
            for (int r = 0; r < 4; ++r) {
                int rl = i * 16 + quad * 4 + r;
                out[((size_t)o * BB + row0 + rl) * 256 + d] = oacc[i][j][r];
            }
        }
    }
}

// ---------------------------------------------------------------------------
extern "C" void kernel_launch(void* const* d_in, const int* in_sizes, int n_in,
                              void* d_out, int out_size, void* d_ws, size_t ws_size,
                              hipStream_t stream)
{
    (void)in_sizes; (void)n_in; (void)out_size; (void)ws_size;

    const float* xA  = (const float*)d_in[0];
    const float* xS  = (const float*)d_in[1];
    const float* xB  = (const float*)d_in[2];
    const float* W1A = (const float*)d_in[3];
    const float* b1A = (const float*)d_in[4];
    const float* W2A = (const float*)d_in[5];
    const float* b2A = (const float*)d_in[6];
    const float* W1S = (const float*)d_in[7];
    const float* b1S = (const float*)d_in[8];
    const float* W2S = (const float*)d_in[9];
    const float* b2S = (const float*)d_in[10];
    const float* W1B = (const float*)d_in[11];
    const float* b1B = (const float*)d_in[12];
    const float* W2B = (const float*)d_in[13];
    const float* b2B = (const float*)d_in[14];
    const float* WgA = (const float*)d_in[15];
    const float* bgA = (const float*)d_in[16];
    const float* WgB = (const float*)d_in[17];
    const float* bgB = (const float*)d_in[18];
    const float* WgS = (const float*)d_in[19];
    const float* bgS = (const float*)d_in[20];

    char* ws = (char*)d_ws;
    f16*   Wp   = (f16*)(ws);                       // 1,572,864 B
    f16*   W2T  = (f16*)(ws + 0x180000);            //   393,216 B
    f16*   Gp   = (f16*)(ws + 0x1E0000);            //    98,304 B
    f16*   hbuf = (f16*)(ws + 0x200000);            // 25,165,824 B
    float* gate = (float*)(ws + 0x200000 + 0x1800000); // 1,835,008 B

    pack_kernel<<<243, 256, 0, stream>>>(W1A, W1S, W1B, W2A, W2S, W2B,
                                         WgA, WgS, WgB, Wp, W2T, Gp);
    l1_kernel<<<dim3(2, 128, 3), 256, 0, stream>>>(
        xA, xS, xB, b1A, b1S, b1B, bgA, bgS, bgB,
        Wp, Gp, hbuf, gate);
    l2_kernel<<<dim3(256, 3), 256, 0, stream>>>(
        hbuf, W2T, b2A, b2S, b2B, gate, (float*)d_out);
}